// Round 6
// baseline (151.898 us; speedup 1.0000x reference)
//
#include <hip/hip_runtime.h>

#define BLOCK 256
#define WPB (BLOCK / 64)

template <int CTRL>
__device__ __forceinline__ float dpp_add(float x) {
    int s = __builtin_amdgcn_update_dpp(0, __float_as_int(x), CTRL, 0xf, 0xf, true);
    return x + __int_as_float(s);
}

// Sum each 32-lane half; 32-lane sums land in lanes 31 and 63.
__device__ __forceinline__ float reduce32(float x) {
    x = dpp_add<0x111>(x);  // row_shr:1
    x = dpp_add<0x112>(x);  // row_shr:2
    x = dpp_add<0x114>(x);  // row_shr:4
    x = dpp_add<0x118>(x);  // row_shr:8
    x = dpp_add<0x142>(x);  // row_bcast:15
    return x;
}

struct Frag { float4 a0, a1, p0, p1, n0, n1; };

__global__ __launch_bounds__(BLOCK) void LossFun_kernel(
    const float* __restrict__ A,
    const float* __restrict__ P,
    const float* __restrict__ N,
    const float* __restrict__ T,     // [B,2]
    const int*   __restrict__ bidx,  // [B]
    float* __restrict__ out,
    int B, float invB)
{
    const int lane  = threadIdx.x & 63;
    const int wid   = threadIdx.x >> 6;
    const int gwave = blockIdx.x * WPB + wid;
    const int nwav  = gridDim.x * WPB;
    const int nquad = B >> 2;            // 4 rows per wave-iteration

    float acc = 0.f;

    auto load_quad = [&](int q) -> Frag {
        Frag f;
        const size_t base = (size_t)q * 512;   // 4 rows x 128 floats
        const float4* pa = (const float4*)(A + base);
        const float4* pp = (const float4*)(P + base);
        const float4* pn = (const float4*)(N + base);
        f.a0 = pa[lane]; f.a1 = pa[lane + 64];
        f.p0 = pp[lane]; f.p1 = pp[lane + 64];
        f.n0 = pn[lane]; f.n1 = pn[lane + 64];
        return f;
    };

    auto compute = [&](const Frag& f, int q) {
        float d0, d1, d2, d3;
        d0 = f.a0.x - f.p0.x; d1 = f.a0.y - f.p0.y; d2 = f.a0.z - f.p0.z; d3 = f.a0.w - f.p0.w;
        float sap0 = d0*d0 + d1*d1 + d2*d2 + d3*d3;
        d0 = f.a0.x - f.n0.x; d1 = f.a0.y - f.n0.y; d2 = f.a0.z - f.n0.z; d3 = f.a0.w - f.n0.w;
        float san0 = d0*d0 + d1*d1 + d2*d2 + d3*d3;
        d0 = f.a1.x - f.p1.x; d1 = f.a1.y - f.p1.y; d2 = f.a1.z - f.p1.z; d3 = f.a1.w - f.p1.w;
        float sap1 = d0*d0 + d1*d1 + d2*d2 + d3*d3;
        d0 = f.a1.x - f.n1.x; d1 = f.a1.y - f.n1.y; d2 = f.a1.z - f.n1.z; d3 = f.a1.w - f.n1.w;
        float san1 = d0*d0 + d1*d1 + d2*d2 + d3*d3;

        sap0 = reduce32(sap0); san0 = reduce32(san0);
        sap1 = reduce32(sap1); san1 = reduce32(san1);

        if ((lane & 31) == 31) {                  // lanes 31, 63 each finish 2 rows
            const int r0 = q * 4 + (lane >> 5);   // rows 4q, 4q+1
            const int r1 = r0 + 2;                // rows 4q+2, 4q+3
            const int b0 = bidx[r0];
            const int b1 = bidx[r1];
            const float2 t0 = ((const float2*)T)[b0];
            const float2 t1 = ((const float2*)T)[b1];
            const float Dap0 = __expf(-t0.x), Dan0 = __expf(-t0.y);
            const float Dap1 = __expf(-t1.x), Dan1 = __expf(-t1.y);
            const float vap0 = __expf(-sqrtf(sap0)), van0 = __expf(-sqrtf(san0));
            const float vap1 = __expf(-sqrtf(sap1)), van1 = __expf(-sqrtf(san1));
            float e;
            e = Dap0 - vap0; acc += Dap0 * e * e;
            e = Dan0 - van0; acc += Dan0 * e * e;
            e = Dap1 - vap1; acc += Dap1 * e * e;
            e = Dan1 - van1; acc += Dan1 * e * e;
        }
    };

    // Explicit ping-pong software pipeline: next quad's 6 loads issue
    // before the current quad's compute consumes its registers.
    int q = gwave;
    if (q < nquad) {
        Frag fa = load_quad(q);
        for (;;) {
            const int qb = q + nwav;
            if (qb >= nquad) { compute(fa, q); break; }
            Frag fb = load_quad(qb);
            compute(fa, q);
            const int qa = qb + nwav;
            if (qa >= nquad) { compute(fb, qb); break; }
            fa = load_quad(qa);
            compute(fb, qb);
            q = qa;
        }
    }

    // acc lives in lanes 31 and 63 of each wave
    acc += __shfl_xor(acc, 32);
    __shared__ float wacc[WPB];
    if (lane == 31) wacc[wid] = acc;
    __syncthreads();
    if (threadIdx.x == 0) {
        float s = 0.f;
        #pragma unroll
        for (int i = 0; i < WPB; ++i) s += wacc[i];
        atomicAdd(out, s * invB);
    }
}

extern "C" void kernel_launch(void* const* d_in, const int* in_sizes, int n_in,
                              void* d_out, int out_size, void* d_ws, size_t ws_size,
                              hipStream_t stream) {
    const float* A    = (const float*)d_in[0];
    const float* P    = (const float*)d_in[1];
    const float* N    = (const float*)d_in[2];
    const float* T    = (const float*)d_in[3];
    const int*   bidx = (const int*)  d_in[4];

    const int B = in_sizes[0] / 128;
    float* out = (float*)d_out;

    (void)hipMemsetAsync(out, 0, sizeof(float), stream);

    // Cached loads (L3 hits are free BW — NT experiment R5 regressed 3%).
    // 2x oversubscription: finished CUs backfill, shrinking the drain tail.
    const int blocks = 4096;
    LossFun_kernel<<<blocks, BLOCK, 0, stream>>>(A, P, N, T, bidx, out, B, 1.0f / (float)B);
}

// Round 7
// 147.163 us; speedup vs baseline: 1.0322x; 1.0322x over previous
//
#include <hip/hip_runtime.h>

#define BLOCK 256
#define WPB (BLOCK / 64)

template <int CTRL>
__device__ __forceinline__ float dpp_add(float x) {
    int s = __builtin_amdgcn_update_dpp(0, __float_as_int(x), CTRL, 0xf, 0xf, true);
    return x + __int_as_float(s);
}

// Sum each 32-lane half; 32-lane sums land in lanes 31 and 63.
__device__ __forceinline__ float reduce32(float x) {
    x = dpp_add<0x111>(x);  // row_shr:1
    x = dpp_add<0x112>(x);  // row_shr:2
    x = dpp_add<0x114>(x);  // row_shr:4
    x = dpp_add<0x118>(x);  // row_shr:8
    x = dpp_add<0x142>(x);  // row_bcast:15
    return x;
}

struct Frag { float4 a0, a1, p0, p1, n0, n1; };

__global__ __launch_bounds__(BLOCK) void LossFun_kernel(
    const float* __restrict__ A,
    const float* __restrict__ P,
    const float* __restrict__ N,
    const float* __restrict__ T,     // [B,2]
    const int*   __restrict__ bidx,  // [B]
    float* __restrict__ out,
    int B, float invB)
{
    const int lane  = threadIdx.x & 63;
    const int wid   = threadIdx.x >> 6;
    const int gwave = blockIdx.x * WPB + wid;
    const int nwav  = gridDim.x * WPB;
    const int nquad = B >> 2;            // 4 rows per wave-iteration

    float acc = 0.f;

    auto load_quad = [&](int q) -> Frag {
        Frag f;
        const size_t base = (size_t)q * 512;   // 4 rows x 128 floats
        const float4* pa = (const float4*)(A + base);
        const float4* pp = (const float4*)(P + base);
        const float4* pn = (const float4*)(N + base);
        f.a0 = pa[lane]; f.a1 = pa[lane + 64];
        f.p0 = pp[lane]; f.p1 = pp[lane + 64];
        f.n0 = pn[lane]; f.n1 = pn[lane + 64];
        return f;
    };

    auto compute = [&](const Frag& f, int q) {
        float d0, d1, d2, d3;
        d0 = f.a0.x - f.p0.x; d1 = f.a0.y - f.p0.y; d2 = f.a0.z - f.p0.z; d3 = f.a0.w - f.p0.w;
        float sap0 = d0*d0 + d1*d1 + d2*d2 + d3*d3;
        d0 = f.a0.x - f.n0.x; d1 = f.a0.y - f.n0.y; d2 = f.a0.z - f.n0.z; d3 = f.a0.w - f.n0.w;
        float san0 = d0*d0 + d1*d1 + d2*d2 + d3*d3;
        d0 = f.a1.x - f.p1.x; d1 = f.a1.y - f.p1.y; d2 = f.a1.z - f.p1.z; d3 = f.a1.w - f.p1.w;
        float sap1 = d0*d0 + d1*d1 + d2*d2 + d3*d3;
        d0 = f.a1.x - f.n1.x; d1 = f.a1.y - f.n1.y; d2 = f.a1.z - f.n1.z; d3 = f.a1.w - f.n1.w;
        float san1 = d0*d0 + d1*d1 + d2*d2 + d3*d3;

        sap0 = reduce32(sap0); san0 = reduce32(san0);
        sap1 = reduce32(sap1); san1 = reduce32(san1);

        if ((lane & 31) == 31) {                  // lanes 31, 63 each finish 2 rows
            const int r0 = q * 4 + (lane >> 5);   // rows 4q, 4q+1
            const int r1 = r0 + 2;                // rows 4q+2, 4q+3
            const int b0 = bidx[r0];
            const int b1 = bidx[r1];
            const float2 t0 = ((const float2*)T)[b0];
            const float2 t1 = ((const float2*)T)[b1];
            const float Dap0 = __expf(-t0.x), Dan0 = __expf(-t0.y);
            const float Dap1 = __expf(-t1.x), Dan1 = __expf(-t1.y);
            const float vap0 = __expf(-sqrtf(sap0)), van0 = __expf(-sqrtf(san0));
            const float vap1 = __expf(-sqrtf(sap1)), van1 = __expf(-sqrtf(san1));
            float e;
            e = Dap0 - vap0; acc += Dap0 * e * e;
            e = Dan0 - van0; acc += Dan0 * e * e;
            e = Dap1 - vap1; acc += Dap1 * e * e;
            e = Dan1 - van1; acc += Dan1 * e * e;
        }
    };

    // Explicit ping-pong software pipeline: next quad's 6 loads issue
    // before the current quad's compute consumes its registers.
    int q = gwave;
    if (q < nquad) {
        Frag fa = load_quad(q);
        for (;;) {
            const int qb = q + nwav;
            if (qb >= nquad) { compute(fa, q); break; }
            Frag fb = load_quad(qb);
            compute(fa, q);
            const int qa = qb + nwav;
            if (qa >= nquad) { compute(fb, qb); break; }
            fa = load_quad(qa);
            compute(fb, qb);
            q = qa;
        }
    }

    // acc lives in lanes 31 and 63 of each wave
    acc += __shfl_xor(acc, 32);
    __shared__ float wacc[WPB];
    if (lane == 31) wacc[wid] = acc;
    __syncthreads();
    if (threadIdx.x == 0) {
        float s = 0.f;
        #pragma unroll
        for (int i = 0; i < WPB; ++i) s += wacc[i];
        atomicAdd(out, s * invB);
    }
}

extern "C" void kernel_launch(void* const* d_in, const int* in_sizes, int n_in,
                              void* d_out, int out_size, void* d_ws, size_t ws_size,
                              hipStream_t stream) {
    const float* A    = (const float*)d_in[0];
    const float* P    = (const float*)d_in[1];
    const float* N    = (const float*)d_in[2];
    const float* T    = (const float*)d_in[3];
    const int*   bidx = (const int*)  d_in[4];

    const int B = in_sizes[0] / 128;
    float* out = (float*)d_out;

    (void)hipMemsetAsync(out, 0, sizeof(float), stream);

    // Best-measured config (R3): cached loads, ping-pong pipeline, exact-fit
    // grid (2048 blocks = 8 blocks/CU, 16 quads/wave). NT loads (R5) and
    // 2x/3x oversubscription (R5/R6) all measured neutral-to-worse.
    const int blocks = 2048;
    LossFun_kernel<<<blocks, BLOCK, 0, stream>>>(A, P, N, T, bidx, out, B, 1.0f / (float)B);
}